// Round 1
// baseline (193.808 us; speedup 1.0000x reference)
//
#include <hip/hip_runtime.h>
#include <math.h>

namespace {

constexpr int RAD  = 6;
constexpr int P    = 13;
constexpr int NWIN = 169;   // P*P
constexpr int NTOT = 338;   // 2 refs * NWIN
constexpr int NCH  = 128;
constexpr int NCLS = 32;
constexpr int W    = 64;
constexpr int HW   = 4096;
constexpr float FOUR_LN2 = 2.772588722239781f;

__device__ __forceinline__ bool better(float va, int ia, float vb, int ib) {
  return (va > vb) || ((va == vb) && (ia < ib));
}

__global__ __launch_bounds__(384) void colorizer_kernel(
    const float* __restrict__ fr,   // [2][2][128][64][64]  (nref,b,c,y,x)
    const float* __restrict__ ft,   // [2][128][64][64]
    const int*  __restrict__ q,     // [2][2][1][256][256]
    float* __restrict__ out) {      // [2][32][64][64]
  const int pix = blockIdx.x;          // b*4096 + y*64 + x
  const int b = pix >> 12;
  const int y = (pix >> 6) & 63;
  const int x = pix & 63;
  const int t = threadIdx.x;
  const int wid  = t >> 6;
  const int lane = t & 63;

  __shared__ float T[NCH];
  __shared__ float s[NTOT];
  __shared__ float wred[6];
  __shared__ float accS[NCLS];
  __shared__ float params[2][8];  // per ref: flag, w0, xs0, ys0, w1, xs1, ys1

  if (t < NCH) T[t] = ft[(b * NCH + t) * HW + (y * W + x)];
  if (t < NCLS) accS[t] = 0.f;
  __syncthreads();

  // ---------- phase 1: correlation dots ----------
  const bool act = (t < NTOT);
  const int i  = (t >= NWIN) ? 1 : 0;
  const int m  = t - i * NWIN;          // 0..168 (garbage ok for t>=338)
  const int dy = m / P;
  const int dx = m - dy * P;
  const int yy = y + dy - RAD;
  const int xx = x + dx - RAD;
  const bool inb = ((unsigned)yy < 64u) && ((unsigned)xx < 64u);

  if (act) {
    float dot = 0.f;
    if (inb) {
      const float* rp = fr + (size_t)((i * 2 + b) * NCH) * HW + yy * W + xx;
      float s0 = 0.f, s1 = 0.f, s2 = 0.f, s3 = 0.f;
      #pragma unroll 4
      for (int c = 0; c < NCH; c += 4) {
        s0 = fmaf(T[c    ], rp[(size_t)(c    ) * HW], s0);
        s1 = fmaf(T[c + 1], rp[(size_t)(c + 1) * HW], s1);
        s2 = fmaf(T[c + 2], rp[(size_t)(c + 2) * HW], s2);
        s3 = fmaf(T[c + 3], rp[(size_t)(c + 3) * HW], s3);
      }
      dot = (s0 + s1) + (s2 + s3);
    }
    s[t] = dot;   // OOB windows are zero-padded -> dot = 0
  }
  __syncthreads();

  // ---------- phase 2: joint softmax over 338 ----------
  const float v = act ? s[t] : -INFINITY;
  float lmax = v;
  for (int off = 32; off > 0; off >>= 1)
    lmax = fmaxf(lmax, __shfl_xor(lmax, off));
  if (lane == 0) wred[wid] = lmax;
  __syncthreads();
  const float gmax = fmaxf(fmaxf(fmaxf(wred[0], wred[1]), fmaxf(wred[2], wred[3])),
                           fmaxf(wred[4], wred[5]));
  const float e = act ? __expf(v - gmax) : 0.f;
  float lsum = e;
  for (int off = 32; off > 0; off >>= 1)
    lsum += __shfl_xor(lsum, off);
  __syncthreads();              // everyone done reading wred (gmax)
  if (lane == 0) wred[wid] = lsum;
  __syncthreads();
  const float gsum = wred[0] + wred[1] + wred[2] + wred[3] + wred[4] + wred[5];
  const float rsum = 1.f / gsum;
  const float prob = e * rsum;
  if (act) s[t] = prob;
  __syncthreads();

  // ---------- phase 3: per-ref top-2 (waves 0,1), stable tie-break ----------
  if (wid < 2) {
    const int ii = wid;
    float v1 = -1.f, v2 = -1.f;
    int i1 = 1 << 20, i2 = 1 << 20;
    for (int mm = lane; mm < NWIN; mm += 64) {
      const float pv = s[ii * NWIN + mm];
      if (better(pv, mm, v1, i1)) { v2 = v1; i2 = i1; v1 = pv; i1 = mm; }
      else if (better(pv, mm, v2, i2)) { v2 = pv; i2 = mm; }
    }
    for (int off = 32; off > 0; off >>= 1) {
      const float u1 = __shfl_xor(v1, off); const int j1 = __shfl_xor(i1, off);
      const float u2 = __shfl_xor(v2, off); const int j2 = __shfl_xor(i2, off);
      if (better(u1, j1, v1, i1)) {
        float nv2; int ni2;
        if (better(v1, i1, u2, j2)) { nv2 = v1; ni2 = i1; }
        else                        { nv2 = u2; ni2 = j2; }
        v1 = u1; i1 = j1; v2 = nv2; i2 = ni2;
      } else if (better(u1, j1, v2, i2)) {
        v2 = u1; i2 = j1;
      }
    }
    if (lane == 0) {
      const float e1 = __expf(v1);
      const float e2 = __expf(v2);
      const float rs = 1.f / (e1 + e2);
      params[ii][0] = (v1 > 0.1f) ? 1.f : 0.f;
      params[ii][1] = e1 * rs;                 // w0
      params[ii][2] = (float)(i1 % P);         // xs0
      params[ii][3] = (float)(i1 / P);         // ys0
      params[ii][4] = e2 * rs;                 // w1
      params[ii][5] = (float)(i2 % P);         // xs1
      params[ii][6] = (float)(i2 / P);         // ys1
    }
  }
  __syncthreads();

  // ---------- phase 4: corr2 + label scatter ----------
  if (act) {
    float val;
    if (params[i][0] != 0.f) {
      const float fdx0 = (float)dx - params[i][2];
      const float fdy0 = (float)dy - params[i][3];
      const float fdx1 = (float)dx - params[i][5];
      const float fdy1 = (float)dy - params[i][6];
      val = params[i][1] * __expf(-FOUR_LN2 * (fdx0 * fdx0 + fdy0 * fdy0))
          + params[i][4] * __expf(-FOUR_LN2 * (fdx1 * fdx1 + fdy1 * fdy1));
    } else {
      val = s[t];
    }
    if (inb) {
      const int cls = q[(size_t)(i * 2 + b) * 65536 + (yy * 4) * 256 + (xx * 4)];
      atomicAdd(&accS[cls], val);
    }
  }
  __syncthreads();

  // ---------- phase 5: write output ----------
  if (t < NCLS) {
    const float sc = (t == 0) ? 1.0f : 1.15f;
    out[(size_t)(b * NCLS + t) * HW + (y * W + x)] = accS[t] * sc;
  }
}

}  // namespace

extern "C" void kernel_launch(void* const* d_in, const int* in_sizes, int n_in,
                              void* d_out, int out_size, void* d_ws, size_t ws_size,
                              hipStream_t stream) {
  const float* fr = (const float*)d_in[0];   // feats_r
  const float* ft = (const float*)d_in[1];   // feats_t
  const int*   q  = (const int*)d_in[2];     // quantized_r
  float* out = (float*)d_out;
  colorizer_kernel<<<dim3(2 * HW), dim3(384), 0, stream>>>(fr, ft, q, out);
}